// Round 10
// baseline (50.673 us; speedup 1.0000x reference)
//
#include <hip/hip_runtime.h>
#include <hip/hip_bf16.h>

#define N_ROWS 8192
#define DIM 128
#define NUM_CLS 512
#define MARGIN_F 0.3f

typedef __attribute__((ext_vector_type(8))) short short8;
typedef __attribute__((ext_vector_type(4))) float f32x4;
typedef __attribute__((ext_vector_type(4))) int int4v;

// ---------------- Kernel S1: class histogram + exclusive prefix, zero cnt --
__global__ __launch_bounds__(512) void hist_kernel(
    const int* __restrict__ tgt, int* __restrict__ class_start,
    int* __restrict__ cnt) {
  __shared__ int h[NUM_CLS];
  const int t = threadIdx.x;
  h[t] = 0;
  cnt[t] = 0;
  __syncthreads();
  for (int i = t; i < N_ROWS; i += 512) atomicAdd(&h[tgt[i]], 1);
  __syncthreads();
  int own = h[t];
  int incl = own;
  for (int off = 1; off < NUM_CLS; off <<= 1) {
    int v = (t >= off) ? h[t - off] : 0;
    __syncthreads();
    incl += v;
    h[t] = incl;
    __syncthreads();
  }
  class_start[t] = incl - own;   // exclusive prefix
}

// ---------------- Kernel S2: scatter (order within class irrelevant) -------
// Mining is max/min (order-independent) and results are keyed to ORIGINAL
// row ids, so non-stable atomicAdd ranks do not affect d_out.
__global__ __launch_bounds__(256) void scatter_kernel(
    const int* __restrict__ tgt, const int* __restrict__ class_start,
    int* __restrict__ cnt, int* __restrict__ sorted_row, int* __restrict__ cls) {
  const int i = blockIdx.x * 256 + threadIdx.x;
  const int c = tgt[i];
  const int pos = class_start[c] + atomicAdd(&cnt[c], 1);
  sorted_row[pos] = i;
  cls[pos] = c;
}

// ---------------- Kernel A: fp32 -> bf16 (fragment-major, sorted), norms ---
// Fragment-major: 16B unit u = c16*256 + kk*64 + l4*16 + l15 holds bf16 elems
// [kk*32+l4*8..+8) of sorted row (c16*16+l15); a panel load is
// xf[c16*256 + kk*64 + lane] (64 lanes contiguous). xbA holds -2x (exact
// pow2 scale) so acc seeded with sqc makes MFMA emit v = sqc - 2s directly.
__global__ __launch_bounds__(256) void prep_kernel(
    const float* __restrict__ x, const int* __restrict__ sorted_row,
    const int* __restrict__ cls, unsigned short* __restrict__ xbA,
    unsigned short* __restrict__ xbB, float2* __restrict__ meta,
    int* __restrict__ apb, int* __restrict__ anb) {
  const int w = threadIdx.x >> 6, l = threadIdx.x & 63;
  const int j = blockIdx.x * 4 + w;            // sorted position
  const int r = sorted_row[j];                 // original row
  float2 v = reinterpret_cast<const float2*>(x + (size_t)r * DIM)[l];
  __hip_bfloat16 b0 = __float2bfloat16(v.x);
  __hip_bfloat16 b1 = __float2bfloat16(v.y);
  __hip_bfloat16 a0 = __float2bfloat16(-2.f * v.x);
  __hip_bfloat16 a1 = __float2bfloat16(-2.f * v.y);
  ushort2 stB, stA;
  stB.x = *reinterpret_cast<unsigned short*>(&b0);
  stB.y = *reinterpret_cast<unsigned short*>(&b1);
  stA.x = *reinterpret_cast<unsigned short*>(&a0);
  stA.y = *reinterpret_cast<unsigned short*>(&a1);
  const int c16 = j >> 4, l15r = j & 15;
  const int unit = c16 * 256 + (l >> 4) * 64 + ((l >> 2) & 3) * 16 + l15r;
  reinterpret_cast<ushort2*>(xbB)[unit * 4 + (l & 3)] = stB;
  reinterpret_cast<ushort2*>(xbA)[unit * 4 + (l & 3)] = stA;

  float s = v.x * v.x + v.y * v.y;
  #pragma unroll
  for (int off = 32; off >= 1; off >>= 1) s += __shfl_xor(s, off);
  if (l == 0) {
    float2 m;
    m.x = s;
    m.y = __int_as_float(cls[j]);     // class bits; only ever bit-compared
    meta[j] = m;
    apb[r] = 0x00000000;              // 0.0f (max identity; diagonal positive)
    anb[r] = 0x7f800000;              // +inf (min identity)
  }
}

// ---------------- Kernel B: fused Gram + batch-hard mining (sorted) --------
// Round-8 streaming 3-pipe pipeline (NO LDS/barriers, ping-pong B prefetch),
// plus class-sorted clean-tile fast path: a 32x32 tile whose col class range
// is disjoint from the wave's row class range (~97%) is all-negative ->
// epilogue is 8 v_min3 instead of ~96 VALU ops. Mixed tiles take the full
// path (covers positives incl. diagonal). Results written to ORIGINAL rows.
__global__ __launch_bounds__(256, 2) void gram_mine_kernel(
    const unsigned short* __restrict__ xbA, const unsigned short* __restrict__ xbB,
    const float2* __restrict__ meta, const int* __restrict__ cls,
    const int* __restrict__ sorted_row, int* __restrict__ apb, int* __restrict__ anb) {
  const int t = threadIdx.x;
  const int w = t >> 6, l = t & 63;
  const int l15 = l & 15, l4 = l >> 4;
  const int rb = blockIdx.x * 128 + w * 32;      // wave's row base (sorted)
  const int chunk = blockIdx.y * 1024;           // 1024 cols per chunk (32 tiles)
  const int chunkb = chunk >> 4;

  const short8* xfA = reinterpret_cast<const short8*>(xbA);
  const short8* xfB = reinterpret_cast<const short8*>(xbB);

  // A fragments (-2x): panels (rb>>4), (rb>>4)+1 (rows rb..rb+31)
  short8 a0[4], a1[4];
  #pragma unroll
  for (int kk = 0; kk < 4; ++kk) {
    a0[kk] = xfA[(rb >> 4) * 256 + kk * 64 + l];
    a1[kk] = xfA[((rb >> 4) + 1) * 256 + kk * 64 + l];
  }

  // wave's row class range (sorted => monotone) + per-lane row classes
  const int rcl_lo = cls[rb], rcl_hi = cls[rb + 31];
  int t_r[8];
  #pragma unroll
  for (int rf = 0; rf < 2; ++rf)
    #pragma unroll
    for (int rg = 0; rg < 4; ++rg)
      t_r[rf * 4 + rg] = __float_as_int(meta[rb + rf * 16 + l4 * 4 + rg].y);

  // mining state on v = sqc - 2*s (row term +sq_r deferred to the end)
  float ap2[8], an2[8];
  #pragma unroll
  for (int i = 0; i < 8; ++i) { ap2[i] = -__builtin_inff(); an2[i] = __builtin_inff(); }

  short8 bb0[8], bb1[8];        // ping-pong full-tile B
  float2 mc0[2], mc1[2];        // (sqc, class) per cf
  int cl0a, cl0b, cl1a, cl1b;   // tile col-class bounds, same parity
  f32x4 accA[2][2], accB[2][2];

#define PREF_B(IDX, BB) do {                                                  \
    const int cb16_ = chunkb + (IDX) * 2;                                     \
    _Pragma("unroll")                                                         \
    for (int kk_ = 0; kk_ < 4; ++kk_) {                                       \
      BB[kk_ * 2 + 0] = xfB[(cb16_ + 0) * 256 + kk_ * 64 + l];                \
      BB[kk_ * 2 + 1] = xfB[(cb16_ + 1) * 256 + kk_ * 64 + l];                \
    } } while (0)

#define META_L(IDX, MC, CLA, CLB) do {                                        \
    MC[0] = meta[chunk + (IDX) * 32 + l15];                                   \
    MC[1] = meta[chunk + (IDX) * 32 + 16 + l15];                              \
    CLA = cls[chunk + (IDX) * 32];                                            \
    CLB = cls[chunk + (IDX) * 32 + 31]; } while (0)

#define MFMA_T(BB, MC, ACC) do {                                              \
    _Pragma("unroll")                                                         \
    for (int cf_ = 0; cf_ < 2; ++cf_) {                                       \
      float s_ = MC[cf_].x;                                                   \
      f32x4 ci_ = {s_, s_, s_, s_};                                           \
      ACC[0][cf_] = ci_; ACC[1][cf_] = ci_;                                   \
    }                                                                         \
    _Pragma("unroll")                                                         \
    for (int kk_ = 0; kk_ < 4; ++kk_) {                                       \
      _Pragma("unroll")                                                       \
      for (int cf_ = 0; cf_ < 2; ++cf_) {                                     \
        ACC[0][cf_] = __builtin_amdgcn_mfma_f32_16x16x32_bf16(                \
            a0[kk_], BB[kk_ * 2 + cf_], ACC[0][cf_], 0, 0, 0);                \
        ACC[1][cf_] = __builtin_amdgcn_mfma_f32_16x16x32_bf16(                \
            a1[kk_], BB[kk_ * 2 + cf_], ACC[1][cf_], 0, 0, 0);                \
      } } } while (0)

#define EPI_T(ACC, MC, CLA, CLB) do {                                         \
    if ((CLB) < rcl_lo || (CLA) > rcl_hi) {                                   \
      /* clean all-negative tile: min3 chains only */                         \
      _Pragma("unroll")                                                       \
      for (int rf_ = 0; rf_ < 2; ++rf_) {                                     \
        _Pragma("unroll")                                                     \
        for (int rg_ = 0; rg_ < 4; ++rg_) {                                   \
          const int ix_ = rf_ * 4 + rg_;                                      \
          an2[ix_] = fminf(fminf(ACC[rf_][0][rg_], ACC[rf_][1][rg_]),         \
                           an2[ix_]);                                         \
        } }                                                                   \
    } else {                                                                  \
      _Pragma("unroll")                                                       \
      for (int cf_ = 0; cf_ < 2; ++cf_) {                                     \
        const int tc_ = __float_as_int(MC[cf_].y);                            \
        _Pragma("unroll")                                                     \
        for (int rf_ = 0; rf_ < 2; ++rf_) {                                   \
          _Pragma("unroll")                                                   \
          for (int rg_ = 0; rg_ < 4; ++rg_) {                                 \
            const int ix_ = rf_ * 4 + rg_;                                    \
            float v_ = ACC[rf_][cf_][rg_];                                    \
            bool p_ = (t_r[ix_] == tc_);                                      \
            ap2[ix_] = p_ ? fmaxf(ap2[ix_], v_) : ap2[ix_];                   \
            an2[ix_] = p_ ? an2[ix_] : fminf(an2[ix_], v_);                   \
          } } }                                                               \
    } } while (0)

  // prologue: tile 0
  PREF_B(0, bb0); META_L(0, mc0, cl0a, cl0b);
  MFMA_T(bb0, mc0, accA); PREF_B(1, bb1); META_L(1, mc1, cl1a, cl1b);

  #pragma unroll 1
  for (int p = 0; p < 15; ++p) {
    const int o = 2 * p + 1;
    MFMA_T(bb1, mc1, accB); PREF_B(o + 1, bb0);
    EPI_T(accA, mc0, cl0a, cl0b); META_L(o + 1, mc0, cl0a, cl0b);
    MFMA_T(bb0, mc0, accA); PREF_B(o + 2, bb1);
    EPI_T(accB, mc1, cl1a, cl1b); META_L(o + 2, mc1, cl1a, cl1b);
  }
  MFMA_T(bb1, mc1, accB);
  EPI_T(accA, mc0, cl0a, cl0b);
  EPI_T(accB, mc1, cl1a, cl1b);

#undef PREF_B
#undef META_L
#undef MFMA_T
#undef EPI_T

  // reduce across the 16 lanes (same l4 group = same rows, different cols)
  #pragma unroll
  for (int i = 0; i < 8; ++i) {
    #pragma unroll
    for (int off = 1; off < 16; off <<= 1) {
      ap2[i] = fmaxf(ap2[i], __shfl_xor(ap2[i], off));
      an2[i] = fminf(an2[i], __shfl_xor(an2[i], off));
    }
  }
  if (l15 == 0) {
    #pragma unroll
    for (int rf = 0; rf < 2; ++rf)
      #pragma unroll
      for (int rg = 0; rg < 4; ++rg) {
        int row = rb + rf * 16 + l4 * 4 + rg;     // sorted index
        int ro = sorted_row[row];                 // original row id
        float sqr = meta[row].x;
        // d^2 = v + sq_r; clamp >=1e-12 commutes with max/min; non-negative
        // floats are int-monotone -> int atomics give exact fp max/min.
        float a2 = fmaxf(ap2[rf * 4 + rg] + sqr, 1e-12f);
        float n2 = fmaxf(an2[rf * 4 + rg] + sqr, 1e-12f);
        atomicMax(apb + ro, __float_as_int(a2));
        atomicMin(anb + ro, __float_as_int(n2));
      }
  }
}

// ---------------- Kernel C: loss = mean(relu(sqrt(ap2)-sqrt(an2)+margin)) --
__global__ __launch_bounds__(1024) void loss_kernel(
    const int4v* __restrict__ apb, const int4v* __restrict__ anb,
    float* __restrict__ out) {
  __shared__ float red[16];
  float s = 0.f;
  for (int i = threadIdx.x; i < N_ROWS / 4; i += 1024) {
    int4v a4 = apb[i], n4 = anb[i];
    #pragma unroll
    for (int j = 0; j < 4; ++j) {
      float ap = sqrtf(__int_as_float(a4[j]));
      float an = sqrtf(__int_as_float(n4[j]));   // +inf sentinel -> relu(-inf)=0
      float li = ap - an + MARGIN_F;
      s += li > 0.f ? li : 0.f;
    }
  }
  #pragma unroll
  for (int off = 32; off >= 1; off >>= 1) s += __shfl_xor(s, off);
  const int w = threadIdx.x >> 6, l = threadIdx.x & 63;
  if (l == 0) red[w] = s;
  __syncthreads();
  if (threadIdx.x < 16) {
    float v = red[threadIdx.x];
    #pragma unroll
    for (int off = 8; off >= 1; off >>= 1) v += __shfl_xor(v, off);
    if (threadIdx.x == 0) out[0] = v / (float)N_ROWS;
  }
}

extern "C" void kernel_launch(void* const* d_in, const int* in_sizes, int n_in,
                              void* d_out, int out_size, void* d_ws, size_t ws_size,
                              hipStream_t stream) {
  const float* x = (const float*)d_in[0];
  const int* tgt = (const int*)d_in[1];
  float* out = (float*)d_out;

  char* ws = (char*)d_ws;
  unsigned short* xbA = (unsigned short*)ws;                 // 2 MB frag-major -2x
  unsigned short* xbB = (unsigned short*)(ws + 2097152);     // 2 MB frag-major  x
  float2* meta = (float2*)(ws + 4194304);                    // 64 KB (sq, cls)
  int* apb = (int*)(ws + 4259840);                           // 32 KB ap^2 bits
  int* anb = (int*)(ws + 4292608);                           // 32 KB an^2 bits
  int* sorted_row = (int*)(ws + 4325376);                    // 32 KB perm
  int* cls = (int*)(ws + 4358144);                           // 32 KB sorted classes
  int* class_start = (int*)(ws + 4390912);                   // 2 KB bins
  int* cnt = (int*)(ws + 4392960);                           // 2 KB counters

  hist_kernel<<<1, 512, 0, stream>>>(tgt, class_start, cnt);
  scatter_kernel<<<32, 256, 0, stream>>>(tgt, class_start, cnt, sorted_row, cls);
  prep_kernel<<<2048, 256, 0, stream>>>(x, sorted_row, cls, xbA, xbB, meta, apb, anb);
  gram_mine_kernel<<<dim3(64, 8), 256, 0, stream>>>(xbA, xbB, meta, cls,
                                                    sorted_row, apb, anb);
  loss_kernel<<<1, 1024, 0, stream>>>((const int4v*)apb, (const int4v*)anb, out);
}

// Round 11
// 45.284 us; speedup vs baseline: 1.1190x; 1.1190x over previous
//
#include <hip/hip_runtime.h>
#include <hip/hip_bf16.h>

#define N_ROWS 8192
#define DIM 128
#define MARGIN_F 0.3f

typedef __attribute__((ext_vector_type(8))) short short8;
typedef __attribute__((ext_vector_type(4))) float f32x4;
typedef __attribute__((ext_vector_type(4))) int int4v;

typedef const void __attribute__((address_space(1)))* gas1_t;
typedef void __attribute__((address_space(3)))* las3_t;

__device__ __forceinline__ void load_lds16(const void* g, void* l) {
  __builtin_amdgcn_global_load_lds((gas1_t)g, (las3_t)l, 16, 0, 0);
}

// ---------------- Kernel A: fp32 -> bf16 (two layouts), norms, init --------
// xbA: fragment-major (-2x): 16B unit u = c16*256 + kk*64 + l4*16 + l15 holds
//   elems [kk*32+l4*8..+8) of row (c16*16+l15); panel load = xfA[c16*256 +
//   kk*64 + lane] (64 lanes contiguous).
// xbBrow: row-major (x), 256 B/row, source for swizzled global_load_lds.
__global__ __launch_bounds__(256) void prep_kernel(
    const float* __restrict__ x, const int* __restrict__ tgt,
    unsigned short* __restrict__ xbA, unsigned short* __restrict__ xbBrow,
    float2* __restrict__ meta, int* __restrict__ apb, int* __restrict__ anb) {
  const int w = threadIdx.x >> 6, l = threadIdx.x & 63;
  const int row = blockIdx.x * 4 + w;
  float2 v = reinterpret_cast<const float2*>(x + (size_t)row * DIM)[l];
  __hip_bfloat16 b0 = __float2bfloat16(v.x);
  __hip_bfloat16 b1 = __float2bfloat16(v.y);
  __hip_bfloat16 a0 = __float2bfloat16(-2.f * v.x);
  __hip_bfloat16 a1 = __float2bfloat16(-2.f * v.y);
  ushort2 stB, stA;
  stB.x = *reinterpret_cast<unsigned short*>(&b0);
  stB.y = *reinterpret_cast<unsigned short*>(&b1);
  stA.x = *reinterpret_cast<unsigned short*>(&a0);
  stA.y = *reinterpret_cast<unsigned short*>(&a1);
  reinterpret_cast<ushort2*>(xbBrow)[(size_t)row * 64 + l] = stB;
  const int c16 = row >> 4, l15r = row & 15;
  const int unit = c16 * 256 + (l >> 4) * 64 + ((l >> 2) & 3) * 16 + l15r;
  reinterpret_cast<ushort2*>(xbA)[unit * 4 + (l & 3)] = stA;

  float s = v.x * v.x + v.y * v.y;
  #pragma unroll
  for (int off = 32; off >= 1; off >>= 1) s += __shfl_xor(s, off);
  if (l == 0) {
    float2 m;
    m.x = s;
    m.y = __int_as_float(tgt[row]);   // raw bit carry; only ever bit-compared
    meta[row] = m;
    apb[row] = 0x00000000;            // 0.0f (max identity; diagonal is positive)
    anb[row] = 0x7f800000;            // +inf (min identity)
  }
}

// ---------------- Kernel B: LDS Gram + mining, counted-vmcnt pipeline ------
// grid (32,16) = 512 blocks = 2/CU; block = 8 waves (512 thr), wave = 32
// rows; block covers 256 rows x 512 cols in 8 slices of 64 cols. Slices are
// staged 2 AHEAD via global_load_lds into a 4-buffer rotation (64 KB LDS);
// the barrier uses raw s_barrier + hand-counted `s_waitcnt vmcnt(4/2/0)`
// (never a full drain mid-loop) so slice s+1/s+2 stage loads stay in flight
// across barriers — removing the compiler's vmcnt(0)-before-barrier stall.
// Buffer safety: writer targets (s+2)%4; any laggard wave is past barrier
// (s-1), so it can only be reading (s-1)%4 or s%4 — disjoint.
__global__ __launch_bounds__(512, 4) void gram_mine_kernel(
    const unsigned short* __restrict__ xbA, const unsigned short* __restrict__ xbBrow,
    const float2* __restrict__ meta, int* __restrict__ apb, int* __restrict__ anb) {
  __shared__ unsigned short Bs[4][64 * 128];   // 4 x 16 KB rotation

  const int t = threadIdx.x;
  const int w = t >> 6, l = t & 63;
  const int l15 = l & 15, l4 = l >> 4;
  const int rb = blockIdx.x * 256 + w * 32;    // wave's global row base
  const int chunk = blockIdx.y * 512;          // block's col range (8 slices)

  const short8* xfA = reinterpret_cast<const short8*>(xbA);

  // A fragments (-2x): panels (rb>>4), (rb>>4)+1
  short8 a0[4], a1[4];
  #pragma unroll
  for (int kk = 0; kk < 4; ++kk) {
    a0[kk] = xfA[(rb >> 4) * 256 + kk * 64 + l];
    a1[kk] = xfA[((rb >> 4) + 1) * 256 + kk * 64 + l];
  }

  // per-lane row classes (C/D layout rows: rb + rf*16 + l4*4 + rg)
  int t_r[8];
  #pragma unroll
  for (int rf = 0; rf < 2; ++rf)
    #pragma unroll
    for (int rg = 0; rg < 4; ++rg)
      t_r[rf * 4 + rg] = __float_as_int(meta[rb + rf * 16 + l4 * 4 + rg].y);

  // mining state on v = sqc - 2*s (row term +sq_r deferred to the end)
  float ap2[8], an2[8];
  #pragma unroll
  for (int i = 0; i < 8; ++i) { ap2[i] = -__builtin_inff(); an2[i] = __builtin_inff(); }

  // stage slice S (64 cols x 128 k = 16 KB) into buffer BUF; swizzled source,
  // linear LDS dest (both-sides rule); 2 load_lds16 per thread.
#define STAGE(BUF, S) do {                                                    \
    const int colbase_ = chunk + (S) * 64;                                    \
    _Pragma("unroll")                                                         \
    for (int r_ = 0; r_ < 2; ++r_) {                                          \
      int c_ = r_ * 512 + t;                                                  \
      int col_ = c_ >> 4;                                                     \
      int off_ = ((c_ & 15) * 16) ^ ((col_ & 7) << 4);                        \
      const char* src_ = reinterpret_cast<const char*>(xbBrow) +              \
                         (size_t)(colbase_ + col_) * 256 + off_;              \
      load_lds16(src_, (char*)(&Bs[BUF][0]) + c_ * 16);                       \
    } } while (0)

  // one slice: stage s+2, counted wait for slice s, raw barrier, MFMA, mine.
#define SLICE(S, VM) do {                                                     \
    if ((S) + 2 < 8) STAGE(((S) + 2) & 3, (S) + 2);                           \
    __builtin_amdgcn_sched_barrier(0);                                        \
    asm volatile("s_waitcnt vmcnt(" #VM ")" ::: "memory");                    \
    __builtin_amdgcn_s_barrier();                                             \
    __builtin_amdgcn_sched_barrier(0);                                        \
    float2 mc_[4];                                                            \
    _Pragma("unroll")                                                         \
    for (int cf_ = 0; cf_ < 4; ++cf_)                                         \
      mc_[cf_] = meta[chunk + (S) * 64 + cf_ * 16 + l15];                     \
    f32x4 acc_[2][4];                                                         \
    _Pragma("unroll")                                                         \
    for (int rf_ = 0; rf_ < 2; ++rf_)                                         \
      _Pragma("unroll")                                                       \
      for (int cf_ = 0; cf_ < 4; ++cf_)                                       \
        acc_[rf_][cf_] = (f32x4){0.f, 0.f, 0.f, 0.f};                         \
    __builtin_amdgcn_s_setprio(1);                                            \
    _Pragma("unroll")                                                         \
    for (int kk_ = 0; kk_ < 4; ++kk_) {                                       \
      _Pragma("unroll")                                                       \
      for (int cf_ = 0; cf_ < 4; ++cf_) {                                     \
        int col_ = cf_ * 16 + l15;                                            \
        int kb_ = (kk_ * 64 + l4 * 16) ^ ((col_ & 7) << 4);                   \
        short8 b_ = *reinterpret_cast<const short8*>(                         \
            reinterpret_cast<const char*>(&Bs[(S) & 3][0]) + col_ * 256 + kb_); \
        acc_[0][cf_] = __builtin_amdgcn_mfma_f32_16x16x32_bf16(               \
            a0[kk_], b_, acc_[0][cf_], 0, 0, 0);                              \
        acc_[1][cf_] = __builtin_amdgcn_mfma_f32_16x16x32_bf16(               \
            a1[kk_], b_, acc_[1][cf_], 0, 0, 0);                              \
      } }                                                                     \
    __builtin_amdgcn_s_setprio(0);                                            \
    _Pragma("unroll")                                                         \
    for (int cf_ = 0; cf_ < 4; ++cf_) {                                       \
      const float sqc_ = mc_[cf_].x;                                          \
      const int tc_ = __float_as_int(mc_[cf_].y);                             \
      _Pragma("unroll")                                                       \
      for (int rf_ = 0; rf_ < 2; ++rf_)                                       \
        _Pragma("unroll")                                                     \
        for (int rg_ = 0; rg_ < 4; ++rg_) {                                   \
          const int ix_ = rf_ * 4 + rg_;                                      \
          float v_ = acc_[rf_][cf_][rg_] + sqc_;   /* -2s + sqc */            \
          bool p_ = (t_r[ix_] == tc_);                                        \
          ap2[ix_] = p_ ? fmaxf(ap2[ix_], v_) : ap2[ix_];                     \
          an2[ix_] = p_ ? an2[ix_] : fminf(an2[ix_], v_);                     \
        } } } while (0)

  // prologue: slices 0 and 1 in flight (4 stage loads outstanding)
  STAGE(0, 0);
  STAGE(1, 1);
  // steady state: wait keeps <=4 stage loads (2 slices) in flight
  SLICE(0, 4);
  SLICE(1, 4);
  SLICE(2, 4);
  SLICE(3, 4);
  SLICE(4, 4);
  SLICE(5, 4);
  SLICE(6, 2);
  SLICE(7, 0);

#undef STAGE
#undef SLICE

  // reduce across the 16 lanes (same l4 group = same rows, different cols)
  #pragma unroll
  for (int i = 0; i < 8; ++i) {
    #pragma unroll
    for (int off = 1; off < 16; off <<= 1) {
      ap2[i] = fmaxf(ap2[i], __shfl_xor(ap2[i], off));
      an2[i] = fminf(an2[i], __shfl_xor(an2[i], off));
    }
  }
  if (l15 == 0) {
    #pragma unroll
    for (int rf = 0; rf < 2; ++rf)
      #pragma unroll
      for (int rg = 0; rg < 4; ++rg) {
        int row = rb + rf * 16 + l4 * 4 + rg;
        float sqr = meta[row].x;
        // d^2 = v + sq_r; clamp >=1e-12 commutes with max/min; non-negative
        // floats are int-monotone -> int atomics give exact fp max/min.
        float a2 = fmaxf(ap2[rf * 4 + rg] + sqr, 1e-12f);
        float n2 = fmaxf(an2[rf * 4 + rg] + sqr, 1e-12f);
        atomicMax(apb + row, __float_as_int(a2));
        atomicMin(anb + row, __float_as_int(n2));
      }
  }
}

// ---------------- Kernel C: loss = mean(relu(sqrt(ap2)-sqrt(an2)+margin)) --
__global__ __launch_bounds__(1024) void loss_kernel(
    const int4v* __restrict__ apb, const int4v* __restrict__ anb,
    float* __restrict__ out) {
  __shared__ float red[16];
  float s = 0.f;
  for (int i = threadIdx.x; i < N_ROWS / 4; i += 1024) {
    int4v a4 = apb[i], n4 = anb[i];
    #pragma unroll
    for (int j = 0; j < 4; ++j) {
      float ap = sqrtf(__int_as_float(a4[j]));
      float an = sqrtf(__int_as_float(n4[j]));   // +inf sentinel -> relu(-inf)=0
      float li = ap - an + MARGIN_F;
      s += li > 0.f ? li : 0.f;
    }
  }
  #pragma unroll
  for (int off = 32; off >= 1; off >>= 1) s += __shfl_xor(s, off);
  const int w = threadIdx.x >> 6, l = threadIdx.x & 63;
  if (l == 0) red[w] = s;
  __syncthreads();
  if (threadIdx.x < 16) {
    float v = red[threadIdx.x];
    #pragma unroll
    for (int off = 8; off >= 1; off >>= 1) v += __shfl_xor(v, off);
    if (threadIdx.x == 0) out[0] = v / (float)N_ROWS;
  }
}

extern "C" void kernel_launch(void* const* d_in, const int* in_sizes, int n_in,
                              void* d_out, int out_size, void* d_ws, size_t ws_size,
                              hipStream_t stream) {
  const float* x = (const float*)d_in[0];
  const int* tgt = (const int*)d_in[1];
  float* out = (float*)d_out;

  char* ws = (char*)d_ws;
  unsigned short* xbA = (unsigned short*)ws;                // 2 MB frag-major -2x
  unsigned short* xbBrow = (unsigned short*)(ws + 2097152); // 2 MB row-major x
  float2* meta = (float2*)(ws + 4194304);                   // 64 KB (sq, tgt)
  int* apb = (int*)(ws + 4194304 + 65536);                  // 32 KB ap^2 bits
  int* anb = (int*)(ws + 4194304 + 65536 + 32768);          // 32 KB an^2 bits

  prep_kernel<<<2048, 256, 0, stream>>>(x, tgt, xbA, xbBrow, meta, apb, anb);
  gram_mine_kernel<<<dim3(32, 16), 512, 0, stream>>>(xbA, xbBrow, meta, apb, anb);
  loss_kernel<<<1, 1024, 0, stream>>>((const int4v*)apb, (const int4v*)anb, out);
}

// Round 12
// 44.776 us; speedup vs baseline: 1.1317x; 1.0113x over previous
//
#include <hip/hip_runtime.h>
#include <hip/hip_bf16.h>

#define N_ROWS 8192
#define DIM 128
#define MARGIN_F 0.3f

typedef __attribute__((ext_vector_type(8))) short short8;
typedef __attribute__((ext_vector_type(4))) float f32x4;
typedef __attribute__((ext_vector_type(4))) int int4v;

typedef const void __attribute__((address_space(1)))* gas1_t;
typedef void __attribute__((address_space(3)))* las3_t;

__device__ __forceinline__ void load_lds16(const void* g, void* l) {
  __builtin_amdgcn_global_load_lds((gas1_t)g, (las3_t)l, 16, 0, 0);
}

// ---------------- Kernel A: fp32 -> bf16 (two layouts), norms, init --------
// xbA: fragment-major (-2x): 16B unit u = c16*256 + kk*64 + l4*16 + l15 holds
//   elems [kk*32+l4*8..+8) of row (c16*16+l15); panel load = xfA[c16*256 +
//   kk*64 + lane] (64 lanes contiguous).
// xbBrow: row-major (x), 256 B/row, source for swizzled global_load_lds.
__global__ __launch_bounds__(256) void prep_kernel(
    const float* __restrict__ x, const int* __restrict__ tgt,
    unsigned short* __restrict__ xbA, unsigned short* __restrict__ xbBrow,
    float2* __restrict__ meta, int* __restrict__ apb, int* __restrict__ anb) {
  const int w = threadIdx.x >> 6, l = threadIdx.x & 63;
  const int row = blockIdx.x * 4 + w;
  float2 v = reinterpret_cast<const float2*>(x + (size_t)row * DIM)[l];
  __hip_bfloat16 b0 = __float2bfloat16(v.x);
  __hip_bfloat16 b1 = __float2bfloat16(v.y);
  __hip_bfloat16 a0 = __float2bfloat16(-2.f * v.x);
  __hip_bfloat16 a1 = __float2bfloat16(-2.f * v.y);
  ushort2 stB, stA;
  stB.x = *reinterpret_cast<unsigned short*>(&b0);
  stB.y = *reinterpret_cast<unsigned short*>(&b1);
  stA.x = *reinterpret_cast<unsigned short*>(&a0);
  stA.y = *reinterpret_cast<unsigned short*>(&a1);
  reinterpret_cast<ushort2*>(xbBrow)[(size_t)row * 64 + l] = stB;
  const int c16 = row >> 4, l15r = row & 15;
  const int unit = c16 * 256 + (l >> 4) * 64 + ((l >> 2) & 3) * 16 + l15r;
  reinterpret_cast<ushort2*>(xbA)[unit * 4 + (l & 3)] = stA;

  float s = v.x * v.x + v.y * v.y;
  #pragma unroll
  for (int off = 32; off >= 1; off >>= 1) s += __shfl_xor(s, off);
  if (l == 0) {
    float2 m;
    m.x = s;
    m.y = __int_as_float(tgt[row]);   // raw bit carry; only ever bit-compared
    meta[row] = m;
    apb[row] = 0x00000000;            // 0.0f (max identity; diagonal is positive)
    anb[row] = 0x7f800000;            // +inf (min identity)
  }
}

// ---------------- Kernel B: LDS Gram + mining, CLEAN counted-vmcnt ---------
// grid (32,32) = 1024 blocks (2 generations at 2/CU); block = 8 waves (512
// thr), wave = 32 rows; block covers 256 rows x 256 cols in 4 slices of 64.
// Column metadata lives in LDS (Ms, staged once in the prologue), so the ONLY
// vmcnt ops in the loop are the stage loads: `s_waitcnt vmcnt(4)` now gives a
// true 2-slice (~1200+ cyc) lead, covering cross-XCD L2/L3 latency (~900 cyc)
// that round 11's meta-polluted count silently destroyed. 4-buffer rotation,
// 4 slices: no LDS buffer is ever reused -> no write/read race by construction.
__global__ __launch_bounds__(512, 4) void gram_mine_kernel(
    const unsigned short* __restrict__ xbA, const unsigned short* __restrict__ xbBrow,
    const float2* __restrict__ meta, int* __restrict__ apb, int* __restrict__ anb) {
  __shared__ unsigned short Bs[4][64 * 128];   // 4 x 16 KB rotation
  __shared__ float2 Ms[256];                   // block's column (sq, class)

  const int t = threadIdx.x;
  const int w = t >> 6, l = t & 63;
  const int l15 = l & 15, l4 = l >> 4;
  const int rb = blockIdx.x * 256 + w * 32;    // wave's global row base
  const int chunk = blockIdx.y * 256;          // block's col range (4 slices)

  const short8* xfA = reinterpret_cast<const short8*>(xbA);

  // A fragments (-2x): panels (rb>>4), (rb>>4)+1
  short8 a0[4], a1[4];
  #pragma unroll
  for (int kk = 0; kk < 4; ++kk) {
    a0[kk] = xfA[(rb >> 4) * 256 + kk * 64 + l];
    a1[kk] = xfA[((rb >> 4) + 1) * 256 + kk * 64 + l];
  }

  // per-lane row classes (C/D layout rows: rb + rf*16 + l4*4 + rg)
  int t_r[8];
  #pragma unroll
  for (int rf = 0; rf < 2; ++rf)
    #pragma unroll
    for (int rg = 0; rg < 4; ++rg)
      t_r[rf * 4 + rg] = __float_as_int(meta[rb + rf * 16 + l4 * 4 + rg].y);

  // mining state on v = sqc - 2*s (row term +sq_r deferred to the end)
  float ap2[8], an2[8];
  #pragma unroll
  for (int i = 0; i < 8; ++i) { ap2[i] = -__builtin_inff(); an2[i] = __builtin_inff(); }

  // stage slice S (64 cols x 128 k = 16 KB) into buffer BUF; swizzled source,
  // linear LDS dest (both-sides rule); 2 load_lds16 per thread.
#define STAGE(BUF, S) do {                                                    \
    const int colbase_ = chunk + (S) * 64;                                    \
    _Pragma("unroll")                                                         \
    for (int r_ = 0; r_ < 2; ++r_) {                                          \
      int c_ = r_ * 512 + t;                                                  \
      int col_ = c_ >> 4;                                                     \
      int off_ = ((c_ & 15) * 16) ^ ((col_ & 7) << 4);                        \
      const char* src_ = reinterpret_cast<const char*>(xbBrow) +              \
                         (size_t)(colbase_ + col_) * 256 + off_;              \
      load_lds16(src_, (char*)(&Bs[BUF][0]) + c_ * 16);                       \
    } } while (0)

  // one slice: stage s+2, counted wait for slice s, raw barrier, MFMA, mine.
  // Meta comes from Ms via ds_read (lgkmcnt) -> vmcnt queue holds stages only.
#define SLICE(S, VM) do {                                                     \
    if ((S) + 2 < 4) STAGE((S) + 2, (S) + 2);                                 \
    __builtin_amdgcn_sched_barrier(0);                                        \
    asm volatile("s_waitcnt vmcnt(" #VM ")" ::: "memory");                    \
    __builtin_amdgcn_s_barrier();                                             \
    __builtin_amdgcn_sched_barrier(0);                                        \
    float2 mc_[4];                                                            \
    _Pragma("unroll")                                                         \
    for (int cf_ = 0; cf_ < 4; ++cf_)                                         \
      mc_[cf_] = Ms[(S) * 64 + cf_ * 16 + l15];                               \
    f32x4 acc_[2][4];                                                         \
    _Pragma("unroll")                                                         \
    for (int rf_ = 0; rf_ < 2; ++rf_)                                         \
      _Pragma("unroll")                                                       \
      for (int cf_ = 0; cf_ < 4; ++cf_)                                       \
        acc_[rf_][cf_] = (f32x4){0.f, 0.f, 0.f, 0.f};                         \
    __builtin_amdgcn_s_setprio(1);                                            \
    _Pragma("unroll")                                                         \
    for (int kk_ = 0; kk_ < 4; ++kk_) {                                       \
      _Pragma("unroll")                                                       \
      for (int cf_ = 0; cf_ < 4; ++cf_) {                                     \
        int col_ = cf_ * 16 + l15;                                            \
        int kb_ = (kk_ * 64 + l4 * 16) ^ ((col_ & 7) << 4);                   \
        short8 b_ = *reinterpret_cast<const short8*>(                         \
            reinterpret_cast<const char*>(&Bs[(S)][0]) + col_ * 256 + kb_);   \
        acc_[0][cf_] = __builtin_amdgcn_mfma_f32_16x16x32_bf16(               \
            a0[kk_], b_, acc_[0][cf_], 0, 0, 0);                              \
        acc_[1][cf_] = __builtin_amdgcn_mfma_f32_16x16x32_bf16(               \
            a1[kk_], b_, acc_[1][cf_], 0, 0, 0);                              \
      } }                                                                     \
    __builtin_amdgcn_s_setprio(0);                                            \
    _Pragma("unroll")                                                         \
    for (int cf_ = 0; cf_ < 4; ++cf_) {                                       \
      const float sqc_ = mc_[cf_].x;                                          \
      const int tc_ = __float_as_int(mc_[cf_].y);                             \
      _Pragma("unroll")                                                       \
      for (int rf_ = 0; rf_ < 2; ++rf_)                                       \
        _Pragma("unroll")                                                     \
        for (int rg_ = 0; rg_ < 4; ++rg_) {                                   \
          const int ix_ = rf_ * 4 + rg_;                                      \
          float v_ = acc_[rf_][cf_][rg_] + sqc_;   /* -2s + sqc */            \
          bool p_ = (t_r[ix_] == tc_);                                        \
          ap2[ix_] = p_ ? fmaxf(ap2[ix_], v_) : ap2[ix_];                     \
          an2[ix_] = p_ ? an2[ix_] : fminf(an2[ix_], v_);                     \
        } } } while (0)

  // prologue: column meta -> LDS (1 load_lds16 for t<128), slices 0,1 in flight
  if (t < 128)
    load_lds16(reinterpret_cast<const char*>(meta + chunk) + t * 16,
               (char*)(&Ms[0]) + t * 16);
  STAGE(0, 0);
  STAGE(1, 1);
  // steady state: vmcnt counts ONLY stage loads (4 = two slices in flight)
  SLICE(0, 4);
  SLICE(1, 4);
  SLICE(2, 2);
  SLICE(3, 0);

#undef STAGE
#undef SLICE

  // reduce across the 16 lanes (same l4 group = same rows, different cols)
  #pragma unroll
  for (int i = 0; i < 8; ++i) {
    #pragma unroll
    for (int off = 1; off < 16; off <<= 1) {
      ap2[i] = fmaxf(ap2[i], __shfl_xor(ap2[i], off));
      an2[i] = fminf(an2[i], __shfl_xor(an2[i], off));
    }
  }
  if (l15 == 0) {
    #pragma unroll
    for (int rf = 0; rf < 2; ++rf)
      #pragma unroll
      for (int rg = 0; rg < 4; ++rg) {
        int row = rb + rf * 16 + l4 * 4 + rg;
        float sqr = meta[row].x;
        // d^2 = v + sq_r; clamp >=1e-12 commutes with max/min; non-negative
        // floats are int-monotone -> int atomics give exact fp max/min.
        float a2 = fmaxf(ap2[rf * 4 + rg] + sqr, 1e-12f);
        float n2 = fmaxf(an2[rf * 4 + rg] + sqr, 1e-12f);
        atomicMax(apb + row, __float_as_int(a2));
        atomicMin(anb + row, __float_as_int(n2));
      }
  }
}

// ---------------- Kernel C: loss = mean(relu(sqrt(ap2)-sqrt(an2)+margin)) --
__global__ __launch_bounds__(1024) void loss_kernel(
    const int4v* __restrict__ apb, const int4v* __restrict__ anb,
    float* __restrict__ out) {
  __shared__ float red[16];
  float s = 0.f;
  for (int i = threadIdx.x; i < N_ROWS / 4; i += 1024) {
    int4v a4 = apb[i], n4 = anb[i];
    #pragma unroll
    for (int j = 0; j < 4; ++j) {
      float ap = sqrtf(__int_as_float(a4[j]));
      float an = sqrtf(__int_as_float(n4[j]));   // +inf sentinel -> relu(-inf)=0
      float li = ap - an + MARGIN_F;
      s += li > 0.f ? li : 0.f;
    }
  }
  #pragma unroll
  for (int off = 32; off >= 1; off >>= 1) s += __shfl_xor(s, off);
  const int w = threadIdx.x >> 6, l = threadIdx.x & 63;
  if (l == 0) red[w] = s;
  __syncthreads();
  if (threadIdx.x < 16) {
    float v = red[threadIdx.x];
    #pragma unroll
    for (int off = 8; off >= 1; off >>= 1) v += __shfl_xor(v, off);
    if (threadIdx.x == 0) out[0] = v / (float)N_ROWS;
  }
}

extern "C" void kernel_launch(void* const* d_in, const int* in_sizes, int n_in,
                              void* d_out, int out_size, void* d_ws, size_t ws_size,
                              hipStream_t stream) {
  const float* x = (const float*)d_in[0];
  const int* tgt = (const int*)d_in[1];
  float* out = (float*)d_out;

  char* ws = (char*)d_ws;
  unsigned short* xbA = (unsigned short*)ws;                // 2 MB frag-major -2x
  unsigned short* xbBrow = (unsigned short*)(ws + 2097152); // 2 MB row-major x
  float2* meta = (float2*)(ws + 4194304);                   // 64 KB (sq, tgt)
  int* apb = (int*)(ws + 4194304 + 65536);                  // 32 KB ap^2 bits
  int* anb = (int*)(ws + 4194304 + 65536 + 32768);          // 32 KB an^2 bits

  prep_kernel<<<2048, 256, 0, stream>>>(x, tgt, xbA, xbBrow, meta, apb, anb);
  gram_mine_kernel<<<dim3(32, 32), 512, 0, stream>>>(xbA, xbBrow, meta, apb, anb);
  loss_kernel<<<1, 1024, 0, stream>>>((const int4v*)apb, (const int4v*)anb, out);
}